// Round 1
// baseline (272.164 us; speedup 1.0000x reference)
//
#include <hip/hip_runtime.h>
#include <math.h>

// CombinedLossSSIMCharbMSE: fused separable 11x11 gaussian (zero-padded) over
// {x, y, x^2, y^2, xy} + elementwise SSIM/charb/MSE combine.
//
// Tile: 64 wide x 32 tall per block, 256 threads.
// Phase A (fused global-read + horizontal filter): 42 halo rows x 8 colgroups
//   of 8 cols; each item reads 18 consecutive floats of pred/target from
//   global (L1 absorbs the 2x overlap) and accumulates into 8 rolling column
//   accumulators per quantity. Writes 5 LDS arrays, stride 65 (2-way bank
//   aliasing only => free).
// Phase B (vertical filter): each thread = 1 column x 8 output rows, rolling
//   accumulation over 18 LDS rows (11.25 LDS reads/px vs 55 naive).
// Epilogue: center pred/target re-read from global (L1-hot), SSIM combine,
//   coalesced store.

#define TW 64
#define TH 32
#define RAD 5
#define KW 11
#define RAW_H (TH + 2 * RAD)   // 42 filtered rows (with vertical halo)
#define F_STRIDE 65            // 64 cols + 1 pad (bank-conflict-free)
#define IMG 512

#define C1F 1e-4f   // (0.01*1)^2
#define C2F 9e-4f   // (0.03*1)^2
#define EPS2 1e-12f // EPS^2

__global__ __launch_bounds__(256, 2)
void CombinedLossSSIMCharbMSE_81372450390186_kernel(
    const float* __restrict__ pred,
    const float* __restrict__ target,
    float* __restrict__ out)
{
    __shared__ float hx[RAW_H * F_STRIDE];
    __shared__ float hy[RAW_H * F_STRIDE];
    __shared__ float hxx[RAW_H * F_STRIDE];
    __shared__ float hyy[RAW_H * F_STRIDE];
    __shared__ float hxy[RAW_H * F_STRIDE];

    const int tid = threadIdx.x;
    const int tx0 = blockIdx.x * TW;
    const int ty0 = blockIdx.y * TH;
    const size_t plane_off = (size_t)blockIdx.z * (IMG * IMG);
    const float* __restrict__ pp = pred + plane_off;
    const float* __restrict__ tp = target + plane_off;
    float* __restrict__ op = out + plane_off;

    // Gaussian weights (sigma=1.5), normalized. Per-thread compute; ~30 inst,
    // negligible vs ~900 FMAs/thread. Stays in registers (compile-time idx).
    float W[KW];
    {
        float s = 0.f;
#pragma unroll
        for (int i = 0; i < KW; ++i) {
            float x = (float)(i - RAD);
            W[i] = __expf(-x * x * (1.0f / (2.0f * 1.5f * 1.5f)));
            s += W[i];
        }
        float inv = 1.0f / s;
#pragma unroll
        for (int i = 0; i < KW; ++i) W[i] *= inv;
    }

    // ---- Phase A: horizontal filter (fused with global read) ----
    // item = r * 8 + cg;  r in [0,42) filtered row, cg = column group of 8.
    for (int item = tid; item < RAW_H * (TW / 8); item += 256) {
        const int r = item >> 3;
        const int cg = item & 7;
        const int c0 = cg * 8;
        const int gy = ty0 - RAD + r;
        const bool oky = (gy >= 0) & (gy < IMG);
        const int rowbase = gy * IMG;

        float ax[8] = {0, 0, 0, 0, 0, 0, 0, 0};
        float ay[8] = {0, 0, 0, 0, 0, 0, 0, 0};
        float axx[8] = {0, 0, 0, 0, 0, 0, 0, 0};
        float ayy[8] = {0, 0, 0, 0, 0, 0, 0, 0};
        float axy[8] = {0, 0, 0, 0, 0, 0, 0, 0};

#pragma unroll
        for (int i = 0; i < 18; ++i) {
            const int gx = tx0 - RAD + c0 + i;
            const bool ok = oky & (gx >= 0) & (gx < IMG);
            const float px = ok ? pp[rowbase + gx] : 0.f;
            const float py = ok ? tp[rowbase + gx] : 0.f;
            const float pxx = px * px;
            const float pyy = py * py;
            const float pxy = px * py;
#pragma unroll
            for (int j = 0; j < 8; ++j) {
                const int m = i - j;          // tap index
                if (m >= 0 && m < KW) {
                    const float w = W[m];
                    ax[j] += w * px;
                    ay[j] += w * py;
                    axx[j] += w * pxx;
                    ayy[j] += w * pyy;
                    axy[j] += w * pxy;
                }
            }
        }
#pragma unroll
        for (int j = 0; j < 8; ++j) {
            const int o = r * F_STRIDE + c0 + j;
            hx[o] = ax[j];
            hy[o] = ay[j];
            hxx[o] = axx[j];
            hyy[o] = ayy[j];
            hxy[o] = axy[j];
        }
    }
    __syncthreads();

    // ---- Phase B: vertical filter + elementwise combine ----
    {
        const int c = tid & 63;            // column in tile
        const int j0 = (tid >> 6) * 8;     // first of 8 output rows

        float mx[8] = {0, 0, 0, 0, 0, 0, 0, 0};
        float my[8] = {0, 0, 0, 0, 0, 0, 0, 0};
        float sxx[8] = {0, 0, 0, 0, 0, 0, 0, 0};
        float syy[8] = {0, 0, 0, 0, 0, 0, 0, 0};
        float sxy[8] = {0, 0, 0, 0, 0, 0, 0, 0};

#pragma unroll
        for (int t = 0; t < 18; ++t) {
            const int o = (j0 + t) * F_STRIDE + c;
            const float fx = hx[o];
            const float fy = hy[o];
            const float fxx = hxx[o];
            const float fyy = hyy[o];
            const float fxy = hxy[o];
#pragma unroll
            for (int j = 0; j < 8; ++j) {
                const int m = t - j;
                if (m >= 0 && m < KW) {
                    const float w = W[m];
                    mx[j] += w * fx;
                    my[j] += w * fy;
                    sxx[j] += w * fxx;
                    syy[j] += w * fyy;
                    sxy[j] += w * fxy;
                }
            }
        }

#pragma unroll
        for (int j = 0; j < 8; ++j) {
            const int gy = ty0 + j0 + j;
            const int gidx = gy * IMG + tx0 + c;
            const float mu_x = mx[j];
            const float mu_y = my[j];
            const float s2x = sxx[j] - mu_x * mu_x;
            const float s2y = syy[j] - mu_y * mu_y;
            const float cxy = sxy[j] - mu_x * mu_y;

            const float A1 = 2.f * mu_x * mu_y + C1F;
            const float A2 = 2.f * cxy + C2F;
            const float B1 = mu_x * mu_x + mu_y * mu_y + C1F;
            const float B2 = s2x + s2y + C2F;
            const float ssim = (A1 / B1) * (A2 / B2);

            const float rp = pp[gidx];   // L1-hot (loaded in phase A)
            const float rt = tp[gidx];
            const float d = rp - rt;
            const float charb = sqrtf(d * d + EPS2);
            // 0.3*charb + 0.1*(20*d^2) + 0.6*(1 - ssim)
            const float loss = 0.3f * charb + 2.0f * (d * d) + 0.6f * (1.f - ssim);
            op[gidx] = loss;
        }
    }
}

extern "C" void kernel_launch(void* const* d_in, const int* in_sizes, int n_in,
                              void* d_out, int out_size, void* d_ws, size_t ws_size,
                              hipStream_t stream) {
    const float* pred = (const float*)d_in[0];
    const float* target = (const float*)d_in[1];
    float* out = (float*)d_out;
    const int planes = in_sizes[0] / (IMG * IMG);   // 16*3 = 48

    dim3 grid(IMG / TW, IMG / TH, planes);          // 8 x 16 x 48 = 6144 blocks
    CombinedLossSSIMCharbMSE_81372450390186_kernel<<<grid, dim3(256), 0, stream>>>(
        pred, target, out);
}